// Round 1
// baseline (510.894 us; speedup 1.0000x reference)
//
#include <hip/hip_runtime.h>
#include <stdint.h>

#define Bq   4
#define Nseq 2048
#define NH   16
#define HD   64
#define DIMD 1024
#define Mtot (Bq*Nseq)   // 8192

typedef float  f32x4  __attribute__((ext_vector_type(4)));
typedef __bf16 bf16x8 __attribute__((ext_vector_type(8)));

typedef __attribute__((address_space(1))) void as1_void;
typedef __attribute__((address_space(3))) void as3_void;

static __device__ __forceinline__ uint16_t f2bf(float f) {
    uint32_t u = __builtin_bit_cast(uint32_t, f);
    u += 0x7fffu + ((u >> 16) & 1u);          // RNE
    return (uint16_t)(u >> 16);
}

static __device__ __forceinline__ void asyncLoad16(const uint16_t* g, uint16_t* l) {
    __builtin_amdgcn_global_load_lds((as1_void*)g, (as3_void*)l, 16, 0, 0);
}

static __device__ __forceinline__ void storeOut(float* p, float v)    { *p = v; }
static __device__ __forceinline__ void storeOut(uint16_t* p, float v) { *p = f2bf(v); }

// ---------------------------------------------------------------------------
// cast fp32 -> bf16 : x (8388608) then Wq,Wk,Wv,Wo (4 x 1048576), dst contiguous
// ---------------------------------------------------------------------------
__global__ void cast_all(const float* __restrict__ x,
                         const float* __restrict__ wq, const float* __restrict__ wk,
                         const float* __restrict__ wv, const float* __restrict__ wo,
                         uint16_t* __restrict__ dst) {
    size_t i = ((size_t)blockIdx.x * blockDim.x + threadIdx.x) * 4;  // elem idx
    const float* src; size_t off;
    if (i < 8388608) { src = x; off = i; }
    else {
        size_t wI = i - 8388608;
        size_t wi = wI >> 20;
        off = wI & 1048575;
        src = (wi == 0) ? wq : (wi == 1) ? wk : (wi == 2) ? wv : wo;
    }
    float4 v = *(const float4*)(src + off);
    ushort4 o;
    o.x = f2bf(v.x); o.y = f2bf(v.y); o.z = f2bf(v.z); o.w = f2bf(v.w);
    *(ushort4*)(dst + i) = o;
}

// ---------------------------------------------------------------------------
// GEMM  C[m][n] = sum_k A[m][k] * W[n][k]   (B^T layout, both row-major over K)
// 128x128 tile, BK=32, 256 thr = 4 waves (2x2), wave = 64x64 via 4x4 MFMA tiles.
// LDS tiles [128 rows][4 chunks of 16B], chunk XOR-swizzled by (row&3).
// Sections: blockIdx.x selects section (QKV fusion) via blocksPerSec.
// ---------------------------------------------------------------------------
template <typename OutT>
__global__ __launch_bounds__(256) void gemm_bt(
    const uint16_t* __restrict__ A, const uint16_t* __restrict__ W0,
    OutT* __restrict__ C0, int K, int Nld, int blocksPerSec,
    size_t wSecStride, size_t cSecStride)
{
    __shared__ __align__(16) uint16_t As[128*32];
    __shared__ __align__(16) uint16_t Bs[128*32];

    const int t = threadIdx.x, lane = t & 63, w = t >> 6;
    const int wr = w >> 1, wc = w & 1;

    const int sec = blockIdx.x / blocksPerSec;
    const int n0  = (blockIdx.x % blocksPerSec) * 128;
    const int m0  = blockIdx.y * 128;
    const uint16_t* Wp = W0 + (size_t)sec * wSecStride;
    OutT* C = C0 + (size_t)sec * cSecStride;

    // staging map: slot s -> row s/4, pos s%4, global chunk = pos ^ (row&3)
    const int s0 = t, s1 = t + 256;
    const int r0 = s0 >> 2, g0 = (s0 & 3) ^ (r0 & 3);
    const int r1 = s1 >> 2, g1 = (s1 & 3) ^ (r1 & 3);
    uint16_t* ldsA0 = As + (size_t)(w*64) * 8;
    uint16_t* ldsA1 = As + (size_t)(256 + w*64) * 8;
    uint16_t* ldsB0 = Bs + (size_t)(w*64) * 8;
    uint16_t* ldsB1 = Bs + (size_t)(256 + w*64) * 8;

    // fragment read offsets (bytes/2 = uint16 elems): addr16 = m*4 + (c ^ (m&3))
    int aoff[4], boff[4];
    {
        const int c = lane >> 4;
        #pragma unroll
        for (int i = 0; i < 4; ++i) {
            int m = wr*64 + i*16 + (lane & 15);
            aoff[i] = (m*4 + (c ^ (m & 3))) * 8;
            int n = wc*64 + i*16 + (lane & 15);
            boff[i] = (n*4 + (c ^ (n & 3))) * 8;
        }
    }

    f32x4 acc[4][4] = {};

    for (int k0 = 0; k0 < K; k0 += 32) {
        __syncthreads();
        asyncLoad16(A  + (size_t)(m0 + r0)*K + k0 + g0*8, ldsA0);
        asyncLoad16(A  + (size_t)(m0 + r1)*K + k0 + g1*8, ldsA1);
        asyncLoad16(Wp + (size_t)(n0 + r0)*K + k0 + g0*8, ldsB0);
        asyncLoad16(Wp + (size_t)(n0 + r1)*K + k0 + g1*8, ldsB1);
        __syncthreads();

        bf16x8 af[4], bfr[4];
        #pragma unroll
        for (int i = 0; i < 4; ++i) af[i]  = *(const bf16x8*)(As + aoff[i]);
        #pragma unroll
        for (int i = 0; i < 4; ++i) bfr[i] = *(const bf16x8*)(Bs + boff[i]);
        #pragma unroll
        for (int mt = 0; mt < 4; ++mt)
            #pragma unroll
            for (int nt = 0; nt < 4; ++nt)
                acc[mt][nt] = __builtin_amdgcn_mfma_f32_16x16x32_bf16(
                    af[mt], bfr[nt], acc[mt][nt], 0, 0, 0);
    }

    #pragma unroll
    for (int mt = 0; mt < 4; ++mt)
        #pragma unroll
        for (int nt = 0; nt < 4; ++nt)
            #pragma unroll
            for (int r = 0; r < 4; ++r) {
                int row = m0 + wr*64 + mt*16 + ((lane >> 4) << 2) + r;
                int col = n0 + wc*64 + nt*16 + (lane & 15);
                storeOut(&C[(size_t)row * Nld + col], acc[mt][nt][r]);
            }
}

// ---------------------------------------------------------------------------
// Flash attention, causal. Q/K/V/O are [B*N, 1024] bf16 (head h at col h*64).
// Block = (q-tile of 64 rows, one (b,h)); 4 waves x 16 q-rows.
// ---------------------------------------------------------------------------
__global__ __launch_bounds__(256) void attn(
    const uint16_t* __restrict__ Q, const uint16_t* __restrict__ K,
    const uint16_t* __restrict__ V, uint16_t* __restrict__ O)
{
    __shared__ __align__(16) uint16_t Qs[64*64];
    __shared__ __align__(16) uint16_t Ks[64*64];
    __shared__ __align__(16) uint16_t Vt[64*64];
    __shared__ __align__(16) uint16_t Ps[4*16*64];

    const int t = threadIdx.x, lane = t & 63, w = t >> 6;
    const int q0 = blockIdx.x * 64;
    const int bh = blockIdx.y, b = bh >> 4, h = bh & 15;
    const size_t rowBase = (size_t)b * Nseq * DIMD + (size_t)h * HD;

    const int s0 = t, s1 = t + 256;
    const int r0 = s0 >> 3, g0 = (s0 & 7) ^ (r0 & 7);
    const int r1 = s1 >> 3, g1 = (s1 & 7) ^ (r1 & 7);

    // ---- stage Q tile, load Q fragments once ----
    asyncLoad16(Q + rowBase + (size_t)(q0 + r0)*DIMD + g0*8, Qs + (w*64)*8);
    asyncLoad16(Q + rowBase + (size_t)(q0 + r1)*DIMD + g1*8, Qs + (256 + w*64)*8);
    __syncthreads();

    bf16x8 qf[2];
    {
        int m = w*16 + (lane & 15);
        #pragma unroll
        for (int ks = 0; ks < 2; ++ks) {
            int c = ks*4 + (lane >> 4);
            qf[ks] = *(const bf16x8*)(Qs + (m*8 + (c ^ (m & 7))) * 8);
        }
    }

    float m_i[4] = {-__builtin_inff(), -__builtin_inff(), -__builtin_inff(), -__builtin_inff()};
    float l_i[4] = {0.f, 0.f, 0.f, 0.f};
    f32x4 o[4] = {};
    const float SL = 0.18033688011112042f;   // (1/sqrt(64)) * log2(e)

    uint16_t* Pw = Ps + w * (16*64);

    for (int kt = 0; kt <= (int)blockIdx.x; ++kt) {
        const int k0 = kt * 64;
        __syncthreads();   // previous iteration's LDS reads done

        // stage K tile (async) and V tile transposed (scalar)
        asyncLoad16(K + rowBase + (size_t)(k0 + r0)*DIMD + g0*8, Ks + (w*64)*8);
        asyncLoad16(K + rowBase + (size_t)(k0 + r1)*DIMD + g1*8, Ks + (256 + w*64)*8);
        #pragma unroll
        for (int ss = 0; ss < 2; ++ss) {
            int s  = ss ? s1 : s0;
            int kr = s >> 3, dc = s & 7;
            uint4 raw = *(const uint4*)(V + rowBase + (size_t)(k0 + kr)*DIMD + dc*8);
            const uint16_t* vb = (const uint16_t*)&raw;
            int ck = kr >> 3;
            #pragma unroll
            for (int j = 0; j < 8; ++j) {
                int d = dc*8 + j;
                Vt[(d*8 + (ck ^ (d & 7))) * 8 + (kr & 7)] = vb[j];
            }
        }
        __syncthreads();

        // ---- S = Q K^T (C-layout: row=(lane>>4)*4+reg, col=lane&15) ----
        f32x4 sv[4];
        #pragma unroll
        for (int nt = 0; nt < 4; ++nt) {
            f32x4 a = {};
            #pragma unroll
            for (int ks = 0; ks < 2; ++ks) {
                int n = nt*16 + (lane & 15);
                int c = ks*4 + (lane >> 4);
                bf16x8 kf = *(const bf16x8*)(Ks + (n*8 + (c ^ (n & 7))) * 8);
                a = __builtin_amdgcn_mfma_f32_16x16x32_bf16(qf[ks], kf, a, 0, 0, 0);
            }
            sv[nt] = a;
        }

        // ---- online softmax ----
        const int colb = k0 + (lane & 15);
        const int rowg = q0 + w*16 + ((lane >> 4) << 2);
        float alpha[4];
        #pragma unroll
        for (int r = 0; r < 4; ++r) {
            int row = rowg + r;
            #pragma unroll
            for (int nt = 0; nt < 4; ++nt) {
                float xv = sv[nt][r] * SL;               // log2-domain, scaled
                if (colb + nt*16 > row) xv = -__builtin_inff();
                sv[nt][r] = xv;
            }
            float rm = fmaxf(fmaxf(sv[0][r], sv[1][r]), fmaxf(sv[2][r], sv[3][r]));
            #pragma unroll
            for (int off = 1; off < 16; off <<= 1) rm = fmaxf(rm, __shfl_xor(rm, off));
            float mn = fmaxf(m_i[r], rm);
            alpha[r] = __builtin_amdgcn_exp2f(m_i[r] - mn);
            float rs = 0.f;
            #pragma unroll
            for (int nt = 0; nt < 4; ++nt) {
                float p = __builtin_amdgcn_exp2f(sv[nt][r] - mn);
                sv[nt][r] = p;
                rs += p;
            }
            #pragma unroll
            for (int off = 1; off < 16; off <<= 1) rs += __shfl_xor(rs, off);
            l_i[r] = l_i[r] * alpha[r] + rs;
            m_i[r] = mn;
        }
        #pragma unroll
        for (int dt = 0; dt < 4; ++dt)
            #pragma unroll
            for (int r = 0; r < 4; ++r) o[dt][r] *= alpha[r];

        // ---- P (C-layout) -> LDS (A-layout via XOR-swizzled rows) ----
        #pragma unroll
        for (int nt = 0; nt < 4; ++nt)
            #pragma unroll
            for (int r = 0; r < 4; ++r) {
                int rr  = ((lane >> 4) << 2) + r;
                int cel = nt*16 + (lane & 15);
                int ch  = cel >> 3;
                Pw[(rr*8 + (ch ^ (rr & 7))) * 8 + (cel & 7)] = f2bf(sv[nt][r]);
            }

        // ---- O += P V ----
        #pragma unroll
        for (int ks = 0; ks < 2; ++ks) {
            int m = lane & 15;
            int c = ks*4 + (lane >> 4);
            bf16x8 pf = *(const bf16x8*)(Pw + (m*8 + (c ^ (m & 7))) * 8);
            #pragma unroll
            for (int dt = 0; dt < 4; ++dt) {
                int n = dt*16 + (lane & 15);
                bf16x8 vf = *(const bf16x8*)(Vt + (n*8 + (c ^ (n & 7))) * 8);
                o[dt] = __builtin_amdgcn_mfma_f32_16x16x32_bf16(pf, vf, o[dt], 0, 0, 0);
            }
        }
    }

    // ---- epilogue: O / l, store bf16 ----
    float inv[4];
    #pragma unroll
    for (int r = 0; r < 4; ++r) inv[r] = 1.0f / l_i[r];
    #pragma unroll
    for (int dt = 0; dt < 4; ++dt)
        #pragma unroll
        for (int r = 0; r < 4; ++r) {
            int row = q0 + w*16 + ((lane >> 4) << 2) + r;
            int col = dt*16 + (lane & 15);
            O[rowBase + (size_t)row * DIMD + col] = f2bf(o[dt][r] * inv[r]);
        }
}

// ---------------------------------------------------------------------------
extern "C" void kernel_launch(void* const* d_in, const int* in_sizes, int n_in,
                              void* d_out, int out_size, void* d_ws, size_t ws_size,
                              hipStream_t stream) {
    const float* x  = (const float*)d_in[0];
    // d_in[1] = causal tril mask, deterministic -> handled analytically
    const float* Wq = (const float*)d_in[2];
    const float* Wk = (const float*)d_in[3];
    const float* Wv = (const float*)d_in[4];
    const float* Wo = (const float*)d_in[5];

    uint16_t* ws  = (uint16_t*)d_ws;
    uint16_t* xb  = ws;                      // 8388608 elems  (x bf16; later reused as attn out)
    uint16_t* wqb = ws + 8388608;            // 4 x 1048576 (Wq,Wk,Wv,Wo bf16, contiguous)
    uint16_t* wob = wqb + 3*1048576;
    uint16_t* qb  = ws + 12582912;           // Q,K,V bf16, 8388608 each
    uint16_t* kb  = qb + 8388608;
    uint16_t* vb  = kb + 8388608;
    uint16_t* ab  = xb;                      // attention output reuses xb

    // 1) cast everything to bf16 (12582912 elems / 4 per thread / 256 per block)
    cast_all<<<12288, 256, 0, stream>>>(x, Wq, Wk, Wv, Wo, ws);

    // 2) fused QKV projection: 3 sections x 8 n-blocks, 64 m-blocks
    gemm_bt<uint16_t><<<dim3(24, 64), 256, 0, stream>>>(
        xb, wqb, qb, DIMD, DIMD, 8, (size_t)1048576, (size_t)8388608);

    // 3) causal flash attention
    attn<<<dim3(32, 64), 256, 0, stream>>>(qb, kb, vb, ab);

    // 4) output projection -> fp32 d_out
    gemm_bt<float><<<dim3(8, 64), 256, 0, stream>>>(
        ab, wob, (float*)d_out, DIMD, DIMD, 8, (size_t)0, (size_t)0);
}

// Round 2
// 325.745 us; speedup vs baseline: 1.5684x; 1.5684x over previous
//
#include <hip/hip_runtime.h>
#include <stdint.h>

#define Bq   4
#define Nseq 2048
#define NH   16
#define HD   64
#define DIMD 1024

typedef float  f32x4  __attribute__((ext_vector_type(4)));
typedef __bf16 bf16x8 __attribute__((ext_vector_type(8)));

typedef __attribute__((address_space(1))) void as1_void;
typedef __attribute__((address_space(3))) void as3_void;

static __device__ __forceinline__ uint16_t f2bf(float f) {
    uint32_t u = __builtin_bit_cast(uint32_t, f);
    u += 0x7fffu + ((u >> 16) & 1u);          // RNE
    return (uint16_t)(u >> 16);
}

static __device__ __forceinline__ void asyncLoad16(const uint16_t* g, uint16_t* l) {
    __builtin_amdgcn_global_load_lds((as1_void*)g, (as3_void*)l, 16, 0, 0);
}

static __device__ __forceinline__ void storeOut(float* p, float v)    { *p = v; }
static __device__ __forceinline__ void storeOut(uint16_t* p, float v) { *p = f2bf(v); }

// ---------------------------------------------------------------------------
// cast fp32 -> bf16 : x (8388608) then Wq,Wk,Wv,Wo (4 x 1048576), dst contiguous
// Wq is pre-scaled by SCALE*log2(e) so attention can use exp2 on raw QK dots.
// ---------------------------------------------------------------------------
__global__ void cast_all(const float* __restrict__ x,
                         const float* __restrict__ wq, const float* __restrict__ wk,
                         const float* __restrict__ wv, const float* __restrict__ wo,
                         uint16_t* __restrict__ dst) {
    size_t i = ((size_t)blockIdx.x * blockDim.x + threadIdx.x) * 4;  // elem idx
    const float* src; size_t off; float scale = 1.0f;
    if (i < 8388608) { src = x; off = i; }
    else {
        size_t wI = i - 8388608;
        size_t wi = wI >> 20;
        off = wI & 1048575;
        src = (wi == 0) ? wq : (wi == 1) ? wk : (wi == 2) ? wv : wo;
        if (wi == 0) scale = 0.18033688011112042f;   // (1/sqrt(64)) * log2(e)
    }
    float4 v = *(const float4*)(src + off);
    ushort4 o;
    o.x = f2bf(v.x * scale); o.y = f2bf(v.y * scale);
    o.z = f2bf(v.z * scale); o.w = f2bf(v.w * scale);
    *(ushort4*)(dst + i) = o;
}

// ---------------------------------------------------------------------------
// GEMM  C[m][n] = sum_k A[m][k] * W[n][k]   (B^T layout, both row-major over K)
// 128x128 tile, BK=32, 256 thr = 4 waves (2x2), wave = 64x64 via 4x4 MFMA tiles.
// Section vSec (V projection) writes TRANSPOSED per (b,h): vt[(b*16+h)*64+d][n]
// so flash attention can stage V^T tiles with global_load_lds.
// ---------------------------------------------------------------------------
template <typename OutT>
__global__ __launch_bounds__(256) void gemm_bt(
    const uint16_t* __restrict__ A, const uint16_t* __restrict__ W0,
    OutT* __restrict__ C0, int K, int Nld, int blocksPerSec,
    size_t wSecStride, size_t cSecStride, uint16_t* __restrict__ vtb, int vSec)
{
    __shared__ __align__(16) uint16_t As[128*32];
    __shared__ __align__(16) uint16_t Bs[128*32];

    const int t = threadIdx.x, lane = t & 63, w = t >> 6;
    const int wr = w >> 1, wc = w & 1;

    const int sec = blockIdx.x / blocksPerSec;
    const int n0  = (blockIdx.x % blocksPerSec) * 128;
    const int m0  = blockIdx.y * 128;
    const uint16_t* Wp = W0 + (size_t)sec * wSecStride;
    OutT* C = C0 + (size_t)sec * cSecStride;

    const int s0 = t, s1 = t + 256;
    const int r0 = s0 >> 2, g0 = (s0 & 3) ^ (r0 & 3);
    const int r1 = s1 >> 2, g1 = (s1 & 3) ^ (r1 & 3);
    uint16_t* ldsA0 = As + (size_t)(w*64) * 8;
    uint16_t* ldsA1 = As + (size_t)(256 + w*64) * 8;
    uint16_t* ldsB0 = Bs + (size_t)(w*64) * 8;
    uint16_t* ldsB1 = Bs + (size_t)(256 + w*64) * 8;

    int aoff[4], boff[4];
    {
        const int c = lane >> 4;
        #pragma unroll
        for (int i = 0; i < 4; ++i) {
            int m = wr*64 + i*16 + (lane & 15);
            aoff[i] = (m*4 + (c ^ (m & 3))) * 8;
            int n = wc*64 + i*16 + (lane & 15);
            boff[i] = (n*4 + (c ^ (n & 3))) * 8;
        }
    }

    f32x4 acc[4][4] = {};

    for (int k0 = 0; k0 < K; k0 += 32) {
        __syncthreads();
        asyncLoad16(A  + (size_t)(m0 + r0)*K + k0 + g0*8, ldsA0);
        asyncLoad16(A  + (size_t)(m0 + r1)*K + k0 + g1*8, ldsA1);
        asyncLoad16(Wp + (size_t)(n0 + r0)*K + k0 + g0*8, ldsB0);
        asyncLoad16(Wp + (size_t)(n0 + r1)*K + k0 + g1*8, ldsB1);
        __syncthreads();

        bf16x8 af[4], bfr[4];
        #pragma unroll
        for (int i = 0; i < 4; ++i) af[i]  = *(const bf16x8*)(As + aoff[i]);
        #pragma unroll
        for (int i = 0; i < 4; ++i) bfr[i] = *(const bf16x8*)(Bs + boff[i]);
        #pragma unroll
        for (int mt = 0; mt < 4; ++mt)
            #pragma unroll
            for (int nt = 0; nt < 4; ++nt)
                acc[mt][nt] = __builtin_amdgcn_mfma_f32_16x16x32_bf16(
                    af[mt], bfr[nt], acc[mt][nt], 0, 0, 0);
    }

    if (vtb != nullptr && sec == vSec) {
        // transposed store: vt[(b*16+h)*64+d][n]; acc r-index runs along n
        #pragma unroll
        for (int mt = 0; mt < 4; ++mt)
            #pragma unroll
            for (int nt = 0; nt < 4; ++nt) {
                int rowg = m0 + wr*64 + mt*16 + ((lane >> 4) << 2);  // token
                int colg = n0 + wc*64 + nt*16 + (lane & 15);         // dim
                int bb = rowg >> 11, nn = rowg & 2047;
                int hh = colg >> 6,  dd = colg & 63;
                ushort4 o4;
                o4.x = f2bf(acc[mt][nt][0]); o4.y = f2bf(acc[mt][nt][1]);
                o4.z = f2bf(acc[mt][nt][2]); o4.w = f2bf(acc[mt][nt][3]);
                *(ushort4*)(vtb + ((size_t)((bb*NH + hh)*HD + dd))*Nseq + nn) = o4;
            }
    } else {
        #pragma unroll
        for (int mt = 0; mt < 4; ++mt)
            #pragma unroll
            for (int nt = 0; nt < 4; ++nt)
                #pragma unroll
                for (int r = 0; r < 4; ++r) {
                    int row = m0 + wr*64 + mt*16 + ((lane >> 4) << 2) + r;
                    int col = n0 + wc*64 + nt*16 + (lane & 15);
                    storeOut(&C[(size_t)row * Nld + col], acc[mt][nt][r]);
                }
    }
}

// ---------------------------------------------------------------------------
// Flash attention, causal, no-max online softmax (exp2-domain, scale folded
// into Wq). Q/K are [B*N,1024] bf16; Vt is [(b*16+h)*64+d][2048] bf16.
// Block = 128 q-rows x one (b,h); 4 waves x 32 q-rows (2 m-tiles each).
// ---------------------------------------------------------------------------
__global__ __launch_bounds__(256, 3) void attn(
    const uint16_t* __restrict__ Q, const uint16_t* __restrict__ K,
    const uint16_t* __restrict__ Vt, uint16_t* __restrict__ O)
{
    __shared__ __align__(16) uint16_t Qs[128*64];   // 16 KB
    __shared__ __align__(16) uint16_t Ks[64*64];    //  8 KB
    __shared__ __align__(16) uint16_t Vs[64*64];    //  8 KB (V^T tile: rows=d)
    __shared__ __align__(16) uint16_t Ps[4*32*64];  // 16 KB (per-wave P)

    const int t = threadIdx.x, lane = t & 63, w = t >> 6;
    const int quad = lane >> 4, c = lane & 15;
    const int qi = (int)gridDim.x - 1 - (int)blockIdx.x;   // heavy tiles first
    const int q0 = qi * 128;
    const int bh = blockIdx.y, b = bh >> 4, h = bh & 15;
    const size_t tokBase = (size_t)b * Nseq;
    const int hcol = h * HD;

    // ---- stage Q tile (128x64), 4 rounds of global_load_lds ----
    #pragma unroll
    for (int i = 0; i < 4; ++i) {
        int s = t + 256*i;
        int row = s >> 3, g = (s & 7) ^ (row & 7);
        asyncLoad16(Q + (tokBase + q0 + row)*DIMD + hcol + g*8,
                    Qs + (size_t)(w*64 + 256*i)*8);
    }
    __syncthreads();

    bf16x8 qf[2][2];
    #pragma unroll
    for (int m = 0; m < 2; ++m)
        #pragma unroll
        for (int ks = 0; ks < 2; ++ks) {
            int row = w*32 + m*16 + c;
            int pos = (ks*4 + quad) ^ (row & 7);
            qf[m][ks] = *(const bf16x8*)(Qs + (size_t)(row*8 + pos)*8);
        }

    f32x4 o[2][4] = {};
    float l_vec[2][4] = {};
    uint16_t* Pw = Ps + w * (32*64);
    const int wrow0 = q0 + w*32;

    const int ktEnd = 2*qi + 2;
    for (int kt = 0; kt < ktEnd; ++kt) {
        const int k0 = kt * 64;
        __syncthreads();   // prior iteration's LDS reads complete
        #pragma unroll
        for (int i = 0; i < 2; ++i) {
            int s = t + 256*i;
            int row = s >> 3, g = (s & 7) ^ (row & 7);
            asyncLoad16(K  + (tokBase + k0 + row)*DIMD + hcol + g*8,
                        Ks + (size_t)(w*64 + 256*i)*8);
            asyncLoad16(Vt + ((size_t)bh*HD + row)*Nseq + k0 + g*8,
                        Vs + (size_t)(w*64 + 256*i)*8);
        }
        __syncthreads();   // staging complete (vmcnt drained by barrier)

        if (k0 > wrow0 + 31) continue;   // fully masked for this wave

        // ---- S = Q K^T  (C-layout: row=quad*4+r, col=lane&15) ----
        f32x4 sv[2][4] = {};
        #pragma unroll
        for (int nt = 0; nt < 4; ++nt) {
            #pragma unroll
            for (int ks = 0; ks < 2; ++ks) {
                int row = nt*16 + c;
                int pos = (ks*4 + quad) ^ (row & 7);
                bf16x8 kf = *(const bf16x8*)(Ks + (size_t)(row*8 + pos)*8);
                sv[0][nt] = __builtin_amdgcn_mfma_f32_16x16x32_bf16(qf[0][ks], kf, sv[0][nt], 0, 0, 0);
                sv[1][nt] = __builtin_amdgcn_mfma_f32_16x16x32_bf16(qf[1][ks], kf, sv[1][nt], 0, 0, 0);
            }
        }

        // ---- causal mask: only diagonal tiles need it (wave-uniform test) ----
        if (k0 + 63 > wrow0) {
            #pragma unroll
            for (int m = 0; m < 2; ++m)
                #pragma unroll
                for (int nt = 0; nt < 4; ++nt)
                    #pragma unroll
                    for (int r = 0; r < 4; ++r) {
                        int rowg = wrow0 + m*16 + quad*4 + r;
                        int colg = k0 + nt*16 + c;
                        if (colg > rowg) sv[m][nt][r] = -340.0f;
                    }
        }

        // ---- p = exp2(s); accumulate row-sum per lane; write P (8B-granule
        //      XOR swizzle -> conflict-free u16 writes, b64-readable frags) ----
        #pragma unroll
        for (int m = 0; m < 2; ++m)
            #pragma unroll
            for (int nt = 0; nt < 4; ++nt)
                #pragma unroll
                for (int r = 0; r < 4; ++r) {
                    float p = __builtin_amdgcn_exp2f(sv[m][nt][r]);
                    l_vec[m][r] += p;
                    int rl  = m*16 + quad*4 + r;
                    int col = nt*16 + c;
                    Pw[rl*64 + (((col >> 2) ^ (rl & 15)) << 2) + (col & 3)] = f2bf(p);
                }

        // ---- O += P V  (A-frag from Pw via two b64 granule reads) ----
        #pragma unroll
        for (int ks = 0; ks < 2; ++ks) {
            bf16x8 pf[2];
            #pragma unroll
            for (int m = 0; m < 2; ++m) {
                int rl = m*16 + c;
                int gA = (ks*8 + quad*2)     ^ c;
                int gB = (ks*8 + quad*2 + 1) ^ c;
                union { ushort4 h[2]; bf16x8 v; } u;
                u.h[0] = *(const ushort4*)(Pw + rl*64 + gA*4);
                u.h[1] = *(const ushort4*)(Pw + rl*64 + gB*4);
                pf[m] = u.v;
            }
            #pragma unroll
            for (int dt = 0; dt < 4; ++dt) {
                int row = dt*16 + c;
                int pos = (ks*4 + quad) ^ (row & 7);
                bf16x8 vf = *(const bf16x8*)(Vs + (size_t)(row*8 + pos)*8);
                o[0][dt] = __builtin_amdgcn_mfma_f32_16x16x32_bf16(pf[0], vf, o[0][dt], 0, 0, 0);
                o[1][dt] = __builtin_amdgcn_mfma_f32_16x16x32_bf16(pf[1], vf, o[1][dt], 0, 0, 0);
            }
        }
    }

    // ---- epilogue: reduce l across the 16 lanes of each quad-row, store ----
    #pragma unroll
    for (int m = 0; m < 2; ++m)
        #pragma unroll
        for (int r = 0; r < 4; ++r) {
            float l = l_vec[m][r];
            #pragma unroll
            for (int off = 1; off < 16; off <<= 1) l += __shfl_xor(l, off);
            float inv = 1.0f / l;
            #pragma unroll
            for (int dt = 0; dt < 4; ++dt) {
                int rowg = wrow0 + m*16 + quad*4 + r;
                int colg = hcol + dt*16 + c;
                O[(tokBase + rowg)*DIMD + colg] = f2bf(o[m][dt][r] * inv);
            }
        }
}

// ---------------------------------------------------------------------------
extern "C" void kernel_launch(void* const* d_in, const int* in_sizes, int n_in,
                              void* d_out, int out_size, void* d_ws, size_t ws_size,
                              hipStream_t stream) {
    const float* x  = (const float*)d_in[0];
    // d_in[1] = causal tril mask, deterministic -> handled analytically
    const float* Wq = (const float*)d_in[2];
    const float* Wk = (const float*)d_in[3];
    const float* Wv = (const float*)d_in[4];
    const float* Wo = (const float*)d_in[5];

    uint16_t* ws  = (uint16_t*)d_ws;
    uint16_t* xb  = ws;                      // x bf16 (later reused as attn out)
    uint16_t* wqb = ws + 8388608;            // Wq,Wk,Wv,Wo bf16 contiguous
    uint16_t* wob = wqb + 3*1048576;
    uint16_t* qb  = ws + 12582912;           // Q
    uint16_t* kb  = qb + 8388608;            // K
    uint16_t* vtb = kb + 8388608;            // V transposed per (b,h)
    uint16_t* ab  = xb;                      // attention output reuses xb

    cast_all<<<12288, 256, 0, stream>>>(x, Wq, Wk, Wv, Wo, ws);

    // QKV projection: Q,K normal; V section (sec==2) stores transposed
    gemm_bt<uint16_t><<<dim3(24, 64), 256, 0, stream>>>(
        xb, wqb, qb, DIMD, DIMD, 8, (size_t)1048576, (size_t)8388608, vtb, 2);

    attn<<<dim3(16, 64), 256, 0, stream>>>(qb, kb, vtb, ab);

    gemm_bt<float><<<dim3(8, 64), 256, 0, stream>>>(
        ab, wob, (float*)d_out, DIMD, DIMD, 8, (size_t)0, (size_t)0, nullptr, -1);
}

// Round 3
// 279.413 us; speedup vs baseline: 1.8285x; 1.1658x over previous
//
#include <hip/hip_runtime.h>
#include <stdint.h>

#define Bq   4
#define Nseq 2048
#define NH   16
#define HD   64
#define DIMD 1024

typedef float  f32x4  __attribute__((ext_vector_type(4)));
typedef __bf16 bf16x8 __attribute__((ext_vector_type(8)));
typedef short  s16x4  __attribute__((ext_vector_type(4)));

typedef __attribute__((address_space(1))) void as1_void;
typedef __attribute__((address_space(3))) void as3_void;

static __device__ __forceinline__ uint16_t f2bf(float f) {
    uint32_t u = __builtin_bit_cast(uint32_t, f);
    u += 0x7fffu + ((u >> 16) & 1u);          // RNE
    return (uint16_t)(u >> 16);
}

// truncation-pack two fp32 -> packed bf16x2 (p>=0, 1-ulp bias, cancels in p/l)
static __device__ __forceinline__ uint32_t pk2(float a, float b) {
    uint32_t ua = __builtin_bit_cast(uint32_t, a);
    uint32_t ub = __builtin_bit_cast(uint32_t, b);
    return (ua >> 16) | (ub & 0xffff0000u);
}

static __device__ __forceinline__ void asyncLoad16(const uint16_t* g, uint16_t* l) {
    __builtin_amdgcn_global_load_lds((as1_void*)g, (as3_void*)l, 16, 0, 0);
}

static __device__ __forceinline__ void storeOut(float* p, float v)    { *p = v; }
static __device__ __forceinline__ void storeOut(uint16_t* p, float v) { *p = f2bf(v); }

// ---------------------------------------------------------------------------
// cast fp32 -> bf16 : x (8388608) then Wq,Wk,Wv,Wo (4 x 1048576), dst contiguous
// Wq is pre-scaled by SCALE*log2(e) so attention can use exp2 on raw QK dots.
// ---------------------------------------------------------------------------
__global__ void cast_all(const float* __restrict__ x,
                         const float* __restrict__ wq, const float* __restrict__ wk,
                         const float* __restrict__ wv, const float* __restrict__ wo,
                         uint16_t* __restrict__ dst) {
    size_t i = ((size_t)blockIdx.x * blockDim.x + threadIdx.x) * 4;  // elem idx
    const float* src; size_t off; float scale = 1.0f;
    if (i < 8388608) { src = x; off = i; }
    else {
        size_t wI = i - 8388608;
        size_t wi = wI >> 20;
        off = wI & 1048575;
        src = (wi == 0) ? wq : (wi == 1) ? wk : (wi == 2) ? wv : wo;
        if (wi == 0) scale = 0.18033688011112042f;   // (1/sqrt(64)) * log2(e)
    }
    float4 v = *(const float4*)(src + off);
    ushort4 o;
    o.x = f2bf(v.x * scale); o.y = f2bf(v.y * scale);
    o.z = f2bf(v.z * scale); o.w = f2bf(v.w * scale);
    *(ushort4*)(dst + i) = o;
}

// ---------------------------------------------------------------------------
// GEMM  C[m][n] = sum_k A[m][k] * W[n][k]   (B^T layout, both row-major over K)
// 128x128 tile, BK=32, 256 thr = 4 waves (2x2), wave = 64x64 via 4x4 MFMA tiles.
// Section vSec (V projection) writes TRANSPOSED per (b,h): vt[(b*16+h)*64+d][n].
// ---------------------------------------------------------------------------
template <typename OutT>
__global__ __launch_bounds__(256) void gemm_bt(
    const uint16_t* __restrict__ A, const uint16_t* __restrict__ W0,
    OutT* __restrict__ C0, int K, int Nld, int blocksPerSec,
    size_t wSecStride, size_t cSecStride, uint16_t* __restrict__ vtb, int vSec)
{
    __shared__ __align__(16) uint16_t As[128*32];
    __shared__ __align__(16) uint16_t Bs[128*32];

    const int t = threadIdx.x, lane = t & 63, w = t >> 6;
    const int wr = w >> 1, wc = w & 1;

    const int sec = blockIdx.x / blocksPerSec;
    const int n0  = (blockIdx.x % blocksPerSec) * 128;
    const int m0  = blockIdx.y * 128;
    const uint16_t* Wp = W0 + (size_t)sec * wSecStride;
    OutT* C = C0 + (size_t)sec * cSecStride;

    const int s0 = t, s1 = t + 256;
    const int r0 = s0 >> 2, g0 = (s0 & 3) ^ (r0 & 3);
    const int r1 = s1 >> 2, g1 = (s1 & 3) ^ (r1 & 3);
    uint16_t* ldsA0 = As + (size_t)(w*64) * 8;
    uint16_t* ldsA1 = As + (size_t)(256 + w*64) * 8;
    uint16_t* ldsB0 = Bs + (size_t)(w*64) * 8;
    uint16_t* ldsB1 = Bs + (size_t)(256 + w*64) * 8;

    int aoff[4], boff[4];
    {
        const int c = lane >> 4;
        #pragma unroll
        for (int i = 0; i < 4; ++i) {
            int m = wr*64 + i*16 + (lane & 15);
            aoff[i] = (m*4 + (c ^ (m & 3))) * 8;
            int n = wc*64 + i*16 + (lane & 15);
            boff[i] = (n*4 + (c ^ (n & 3))) * 8;
        }
    }

    f32x4 acc[4][4] = {};

    for (int k0 = 0; k0 < K; k0 += 32) {
        __syncthreads();
        asyncLoad16(A  + (size_t)(m0 + r0)*K + k0 + g0*8, ldsA0);
        asyncLoad16(A  + (size_t)(m0 + r1)*K + k0 + g1*8, ldsA1);
        asyncLoad16(Wp + (size_t)(n0 + r0)*K + k0 + g0*8, ldsB0);
        asyncLoad16(Wp + (size_t)(n0 + r1)*K + k0 + g1*8, ldsB1);
        __syncthreads();

        bf16x8 af[4], bfr[4];
        #pragma unroll
        for (int i = 0; i < 4; ++i) af[i]  = *(const bf16x8*)(As + aoff[i]);
        #pragma unroll
        for (int i = 0; i < 4; ++i) bfr[i] = *(const bf16x8*)(Bs + boff[i]);
        #pragma unroll
        for (int mt = 0; mt < 4; ++mt)
            #pragma unroll
            for (int nt = 0; nt < 4; ++nt)
                acc[mt][nt] = __builtin_amdgcn_mfma_f32_16x16x32_bf16(
                    af[mt], bfr[nt], acc[mt][nt], 0, 0, 0);
    }

    if (vtb != nullptr && sec == vSec) {
        #pragma unroll
        for (int mt = 0; mt < 4; ++mt)
            #pragma unroll
            for (int nt = 0; nt < 4; ++nt) {
                int rowg = m0 + wr*64 + mt*16 + ((lane >> 4) << 2);  // token
                int colg = n0 + wc*64 + nt*16 + (lane & 15);         // dim
                int bb = rowg >> 11, nn = rowg & 2047;
                int hh = colg >> 6,  dd = colg & 63;
                ushort4 o4;
                o4.x = f2bf(acc[mt][nt][0]); o4.y = f2bf(acc[mt][nt][1]);
                o4.z = f2bf(acc[mt][nt][2]); o4.w = f2bf(acc[mt][nt][3]);
                *(ushort4*)(vtb + ((size_t)((bb*NH + hh)*HD + dd))*Nseq + nn) = o4;
            }
    } else {
        #pragma unroll
        for (int mt = 0; mt < 4; ++mt)
            #pragma unroll
            for (int nt = 0; nt < 4; ++nt)
                #pragma unroll
                for (int r = 0; r < 4; ++r) {
                    int row = m0 + wr*64 + mt*16 + ((lane >> 4) << 2) + r;
                    int col = n0 + wc*64 + nt*16 + (lane & 15);
                    storeOut(&C[(size_t)row * Nld + col], acc[mt][nt][r]);
                }
    }
}

// ---------------------------------------------------------------------------
// Flash attention, causal, no-max online softmax, S^T formulation:
//   S^T = K.Q^T  (C-layout row = kv, col = q)  -> P^T in registers is exactly
//   the B-operand of mfma_f32_16x16x16bf16_1k -> O^T = V^T.P^T, no P LDS trip.
// Double-buffered K/V staging, ONE barrier per k-tile. Blocks pair q-tiles
// (p, 15-p) so every block does 34 k-tile iterations (uniform cost).
// Q/K: [B*N,1024] bf16; Vt: [(b*16+h)*64+d][2048] bf16.
// ---------------------------------------------------------------------------
__global__ __launch_bounds__(256, 3) void attn(
    const uint16_t* __restrict__ Q, const uint16_t* __restrict__ K,
    const uint16_t* __restrict__ Vt, uint16_t* __restrict__ O)
{
    __shared__ __align__(16) uint16_t Qs[128*64];     // 16 KB
    __shared__ __align__(16) uint16_t Kb[2][64*64];   // 16 KB
    __shared__ __align__(16) uint16_t Vb[2][64*64];   // 16 KB (V^T tiles, rows=d)

    const int t = threadIdx.x, lane = t & 63, w = t >> 6;
    const int quad = lane >> 4, c = lane & 15;
    const int pair = blockIdx.x;                  // 0..7
    const int bh = blockIdx.y, b = bh >> 4, h = bh & 15;
    const size_t tokBase = (size_t)b * Nseq;
    const int hcol = h * HD;

    #define STAGE_Q(q0_)                                                     \
        _Pragma("unroll")                                                    \
        for (int i = 0; i < 4; ++i) {                                        \
            int s = t + 256*i;                                               \
            int row = s >> 3, gg = (s & 7) ^ (row & 7);                      \
            asyncLoad16(Q + (tokBase + (q0_) + row)*DIMD + hcol + gg*8,      \
                        Qs + (size_t)(w*64 + 256*i)*8);                      \
        }

    #define STAGE_KV(k0_, buf_)                                             \
        _Pragma("unroll")                                                    \
        for (int i = 0; i < 2; ++i) {                                        \
            int s = t + 256*i;                                               \
            int row = s >> 3, gg = (s & 7) ^ (row & 7);                      \
            asyncLoad16(K + (tokBase + (k0_) + row)*DIMD + hcol + gg*8,      \
                        Kb[buf_] + (size_t)(w*64 + 256*i)*8);                \
            asyncLoad16(Vt + ((size_t)bh*HD + row)*Nseq + (k0_) + gg*8,      \
                        Vb[buf_] + (size_t)(w*64 + 256*i)*8);                \
        }

    STAGE_Q(pair*128);
    STAGE_KV(0, 0);

    int g = 0;   // global tile counter -> buffer parity
    for (int sp = 0; sp < 2; ++sp) {
        const int qi = sp ? (15 - pair) : pair;
        const int q0 = qi * 128;
        const int wrow0 = q0 + w*32;
        const int end = 2*qi + 2;

        bf16x8 qf[2][2];
        f32x4  o[2][4] = {};
        float  l_lane[2] = {0.f, 0.f};

        for (int kt = 0; kt < end; ++kt, ++g) {
            const int cur = g & 1, nxt = cur ^ 1;
            const int k0 = kt * 64;
            __syncthreads();          // buf[cur] ready; buf[nxt] free to fill

            if (kt == 0) {
                #pragma unroll
                for (int qt = 0; qt < 2; ++qt)
                    #pragma unroll
                    for (int ks = 0; ks < 2; ++ks) {
                        int row = w*32 + qt*16 + c;
                        int pos = (ks*4 + quad) ^ (row & 7);
                        qf[qt][ks] = *(const bf16x8*)(Qs + (size_t)(row*8 + pos)*8);
                    }
            }

            // prefetch next tile (this sub-problem, or B's tile 0)
            if (kt + 1 < end)      { STAGE_KV((kt+1)*64, nxt); }
            else if (sp == 0)      { STAGE_KV(0, nxt); }
            if (sp == 0 && kt == 1) { STAGE_Q((15-pair)*128); }

            if (k0 > wrow0 + 31) continue;     // wave fully above diagonal

            const uint16_t* Ks = Kb[cur];
            const uint16_t* Vs = Vb[cur];

            // ---- S^T = K.Q^T : per (nt=kv-tile, qt) ----
            f32x4 sv[2][4] = {};
            #pragma unroll
            for (int nt = 0; nt < 4; ++nt)
                #pragma unroll
                for (int ks = 0; ks < 2; ++ks) {
                    int row = nt*16 + c;
                    int pos = (ks*4 + quad) ^ (row & 7);
                    bf16x8 kf = *(const bf16x8*)(Ks + (size_t)(row*8 + pos)*8);
                    sv[0][nt] = __builtin_amdgcn_mfma_f32_16x16x32_bf16(kf, qf[0][ks], sv[0][nt], 0, 0, 0);
                    sv[1][nt] = __builtin_amdgcn_mfma_f32_16x16x32_bf16(kf, qf[1][ks], sv[1][nt], 0, 0, 0);
                }

            // ---- causal mask (diagonal tiles only; kv > q -> -inf) ----
            if (k0 + 63 > wrow0) {
                #pragma unroll
                for (int qt = 0; qt < 2; ++qt)
                    #pragma unroll
                    for (int nt = 0; nt < 4; ++nt)
                        #pragma unroll
                        for (int r = 0; r < 4; ++r) {
                            int kvg = k0 + nt*16 + quad*4 + r;
                            int qg  = wrow0 + qt*16 + c;
                            if (kvg > qg) sv[qt][nt][r] = -340.0f;
                        }
            }

            // ---- p = exp2(s); row-sum per lane; pack P^T as B-frags ----
            s16x4 pb[2][4];
            #pragma unroll
            for (int qt = 0; qt < 2; ++qt)
                #pragma unroll
                for (int nt = 0; nt < 4; ++nt) {
                    float p0 = __builtin_amdgcn_exp2f(sv[qt][nt][0]);
                    float p1 = __builtin_amdgcn_exp2f(sv[qt][nt][1]);
                    float p2 = __builtin_amdgcn_exp2f(sv[qt][nt][2]);
                    float p3 = __builtin_amdgcn_exp2f(sv[qt][nt][3]);
                    l_lane[qt] += (p0 + p1) + (p2 + p3);
                    union { uint32_t u[2]; s16x4 v; } pu;
                    pu.u[0] = pk2(p0, p1);
                    pu.u[1] = pk2(p2, p3);
                    pb[qt][nt] = pu.v;
                }

            // ---- O^T += V^T.P^T  (K=16 steps; A=V^T rows from LDS b64) ----
            #pragma unroll
            for (int s4 = 0; s4 < 4; ++s4)
                #pragma unroll
                for (int dt = 0; dt < 4; ++dt) {
                    int row = dt*16 + c;                    // d
                    int chunk = s4*2 + (quad >> 1);
                    int pos = chunk ^ (row & 7);
                    s16x4 vf = *(const s16x4*)(Vs + (size_t)(row*8 + pos)*8 + (quad & 1)*4);
                    o[0][dt] = __builtin_amdgcn_mfma_f32_16x16x16bf16_1k(vf, pb[0][s4], o[0][dt], 0, 0, 0);
                    o[1][dt] = __builtin_amdgcn_mfma_f32_16x16x16bf16_1k(vf, pb[1][s4], o[1][dt], 0, 0, 0);
                }
        }

        // ---- epilogue: reduce l over quads, scale, store O^T packed ----
        #pragma unroll
        for (int qt = 0; qt < 2; ++qt) {
            float l = l_lane[qt];
            l += __shfl_xor(l, 16);
            l += __shfl_xor(l, 32);
            float inv = 1.0f / l;
            int tok = (int)(q0 + w*32 + qt*16 + c);
            #pragma unroll
            for (int dt = 0; dt < 4; ++dt) {
                ushort4 o4;
                o4.x = f2bf(o[qt][dt][0] * inv);
                o4.y = f2bf(o[qt][dt][1] * inv);
                o4.z = f2bf(o[qt][dt][2] * inv);
                o4.w = f2bf(o[qt][dt][3] * inv);
                *(ushort4*)(O + (tokBase + tok)*DIMD + hcol + dt*16 + quad*4) = o4;
            }
        }
    }
    #undef STAGE_Q
    #undef STAGE_KV
}

// ---------------------------------------------------------------------------
extern "C" void kernel_launch(void* const* d_in, const int* in_sizes, int n_in,
                              void* d_out, int out_size, void* d_ws, size_t ws_size,
                              hipStream_t stream) {
    const float* x  = (const float*)d_in[0];
    // d_in[1] = causal tril mask, deterministic -> handled analytically
    const float* Wq = (const float*)d_in[2];
    const float* Wk = (const float*)d_in[3];
    const float* Wv = (const float*)d_in[4];
    const float* Wo = (const float*)d_in[5];

    uint16_t* ws  = (uint16_t*)d_ws;
    uint16_t* xb  = ws;                      // x bf16 (later reused as attn out)
    uint16_t* wqb = ws + 8388608;            // Wq,Wk,Wv,Wo bf16 contiguous
    uint16_t* wob = wqb + 3*1048576;
    uint16_t* qb  = ws + 12582912;           // Q
    uint16_t* kb  = qb + 8388608;            // K
    uint16_t* vtb = kb + 8388608;            // V transposed per (b,h)
    uint16_t* ab  = xb;                      // attention output reuses xb

    cast_all<<<12288, 256, 0, stream>>>(x, Wq, Wk, Wv, Wo, ws);

    gemm_bt<uint16_t><<<dim3(24, 64), 256, 0, stream>>>(
        xb, wqb, qb, DIMD, DIMD, 8, (size_t)1048576, (size_t)8388608, vtb, 2);

    attn<<<dim3(8, 64), 256, 0, stream>>>(qb, kb, vtb, ab);

    gemm_bt<float><<<dim3(8, 64), 256, 0, stream>>>(
        ab, wob, (float*)d_out, DIMD, DIMD, 8, (size_t)0, (size_t)0, nullptr, -1);
}